// Round 4
// baseline (1881.123 us; speedup 1.0000x reference)
//
#include <hip/hip_runtime.h>
#include <hip/hip_bf16.h>
#include <float.h>
#include <limits.h>

#define NROWS 131072
#define DIM   256
#define NLVL  4
#define KC    1024
#define MARGIN 6.0f
#define CAP   16

typedef __attribute__((ext_vector_type(8))) short bf16x8;
typedef __attribute__((ext_vector_type(4))) float f32x4;
typedef __attribute__((ext_vector_type(4))) unsigned short us4;

__device__ __forceinline__ unsigned short f2b(float f){
  __hip_bfloat16 h = __float2bfloat16(f);
  return *reinterpret_cast<unsigned short*>(&h);
}

// square with a scheduling barrier so -ffp-contract can never fuse the
// multiply into a following add (numpy materializes cb*cb before summing)
__device__ __forceinline__ float sqb(float x){
  float s = x * x;
  asm volatile("" : "+v"(s));
  return s;
}

__device__ __forceinline__ void ins4(float (&s)[4], int (&ix)[4], float v, int ci){
  if (v < s[3]){
    s[3]=v; ix[3]=ci;
    if (s[3]<s[2]){ float t=s[2]; s[2]=s[3]; s[3]=t; int u=ix[2]; ix[2]=ix[3]; ix[3]=u; }
    if (s[2]<s[1]){ float t=s[1]; s[1]=s[2]; s[2]=t; int u=ix[1]; ix[1]=ix[2]; ix[2]=u; }
    if (s[1]<s[0]){ float t=s[0]; s[0]=s[1]; s[1]=t; int u=ix[0]; ix[0]=ix[1]; ix[1]=u; }
  }
}

// bf16 copy of codebooks (phase-A input only)
__global__ void prep_cbb(const float* __restrict__ cb, unsigned short* __restrict__ cbb){
  const int wave = threadIdx.x >> 6, lane = threadIdx.x & 63;
  const int c = blockIdx.x * 4 + wave;                  // 0..4095
  const size_t off = (size_t)c * DIM + lane * 4;
  const float4 v = *reinterpret_cast<const float4*>(cb + off);
  us4 u = { f2b(v.x), f2b(v.y), f2b(v.z), f2b(v.w) };
  *reinterpret_cast<us4*>(cbb + off) = u;
}

// ||c||^2 replicating numpy fp32 pairwise_sum of materialized cb*cb:
// n=256 -> two 128 blocks; each: r[0..7] 16-term sequential chains,
// ((r0+r1)+(r2+r3))+((r4+r5)+(r6+r7)); total = B0+B1.
__global__ void prep_cn(const float* __restrict__ cb, float* __restrict__ cnx){
  const int c = blockIdx.x * 64 + threadIdx.x;          // 0..4095
  const float* p = cb + (size_t)c * DIM;
  float blk[2];
  for (int b = 0; b < 2; ++b){
    float r[8];
#pragma unroll
    for (int j = 0; j < 8; ++j) r[j] = sqb(p[b*128 + j]);
    for (int i = 8; i < 128; i += 8)
#pragma unroll
      for (int j = 0; j < 8; ++j) r[j] += sqb(p[b*128 + i + j]);
    blk[b] = ((r[0]+r[1]) + (r[2]+r[3])) + ((r[4]+r[5]) + (r[6]+r[7]));
  }
  cnx[c] = blk[0] + blk[1];
}

// res_bf16 = bf16(features)  (level-0 phase-A input)
__global__ void prep_res(const float* __restrict__ feat, unsigned short* __restrict__ resb){
  const size_t i = ((size_t)blockIdx.x * 256 + threadIdx.x) * 4;
  const float4 v = *reinterpret_cast<const float4*>(feat + i);
  us4 u = { f2b(v.x), f2b(v.y), f2b(v.z), f2b(v.w) };
  *reinterpret_cast<us4*>(resb + i) = u;
}

// One level. Phase A: bf16 MFMA approx scores + margin-6 candidates.
// Phase B: exact numpy-fp32 semantics re-rank (sequential fmaf chain over d,
// residual reconstructed as the elementwise fp32 chain from features).
template<int LVL>
__global__ __launch_bounds__(512)
void rvq_level(const float* __restrict__ feat,
               const float* __restrict__ cb32,          // [4][1024][256] fp32
               const unsigned short* __restrict__ cbb_l,// this level's bf16 codebook
               const float* __restrict__ cnx_l,         // this level's numpy-tree ||c||^2
               unsigned short* __restrict__ resb,       // residual bf16 [N][256]
               int* __restrict__ idxw,                  // [4][N]
               float* __restrict__ out)
{
  __shared__ float Ls[32][132];
  __shared__ int   Li[32][132];
  __shared__ float Rres[32][260];                       // padded: bank spread
  __shared__ int   cand[32][CAP];
  __shared__ int   cnt[32];
  __shared__ int   ovf[32];
  __shared__ int   win[32];
  __shared__ int   cls[32];                             // 0 done, 1 pair, 2 brute
  __shared__ int   rl[32], bl[32];
  __shared__ int   nrl, nbl, npairs;
  __shared__ int   pr[512], pc[512];
  __shared__ float ps[512];

  const int tid  = threadIdx.x;
  const int wave = tid >> 6;
  const int lane = tid & 63;
  const int r16  = lane & 15;
  const int quad = lane >> 4;
  const size_t rowbase = (size_t)blockIdx.x * 32;

  if (tid < 32){ cnt[tid] = 0; ovf[tid] = 0; }
  if (tid == 0){ nrl = 0; nbl = 0; npairs = 0; }

  // ---- Phase A: bf16 MFMA scoring (validated vs fp64 in r1-r3) ---------
  bf16x8 Bf[2][8];
#pragma unroll
  for (int rt = 0; rt < 2; ++rt)
#pragma unroll
    for (int kk = 0; kk < 8; ++kk)
      Bf[rt][kk] = *reinterpret_cast<const bf16x8*>(
          resb + (rowbase + rt*16 + r16) * DIM + kk*32 + quad*8);

  float ts0[4] = {FLT_MAX,FLT_MAX,FLT_MAX,FLT_MAX};
  int   ti0[4] = {INT_MAX,INT_MAX,INT_MAX,INT_MAX};
  float ts1[4] = {FLT_MAX,FLT_MAX,FLT_MAX,FLT_MAX};
  int   ti1[4] = {INT_MAX,INT_MAX,INT_MAX,INT_MAX};

  for (int t = 0; t < 8; ++t){
    const int c0 = wave * 128 + t * 16;
    bf16x8 Af[8];
#pragma unroll
    for (int kk = 0; kk < 8; ++kk)
      Af[kk] = *reinterpret_cast<const bf16x8*>(
          cbb_l + (size_t)(c0 + r16) * DIM + kk*32 + quad*8);
    f32x4 a0 = {0.f,0.f,0.f,0.f}, a1 = {0.f,0.f,0.f,0.f};
#pragma unroll
    for (int kk = 0; kk < 8; ++kk){
      a0 = __builtin_amdgcn_mfma_f32_16x16x32_bf16(Af[kk], Bf[0][kk], a0, 0, 0, 0);
      a1 = __builtin_amdgcn_mfma_f32_16x16x32_bf16(Af[kk], Bf[1][kk], a1, 0, 0, 0);
    }
#pragma unroll
    for (int r = 0; r < 4; ++r){
      const int ci = c0 + quad*4 + r;
      const float cn = cnx_l[ci];
      ins4(ts0, ti0, cn - 2.0f * a0[r], ci);
      ins4(ts1, ti1, cn - 2.0f * a1[r], ci);
    }
  }

  const int sid = (wave * 4 + quad) * 4;
#pragma unroll
  for (int e = 0; e < 4; ++e){
    Ls[r16][sid+e]    = ts0[e];  Li[r16][sid+e]    = ti0[e];
    Ls[16+r16][sid+e] = ts1[e];  Li[16+r16][sid+e] = ti1[e];
  }
  __syncthreads();

  // ---- per-row min + candidate collection + stream-overflow flag -------
  {
    const int row = tid >> 4, j = tid & 15;
    float bs = FLT_MAX; int bi = INT_MAX;
    for (int e = 0; e < 8; ++e){
      const float s = Ls[row][j*8+e]; const int ii = Li[row][j*8+e];
      if (s < bs || (s == bs && ii < bi)){ bs = s; bi = ii; }
    }
#pragma unroll
    for (int m = 1; m < 16; m <<= 1){
      const float os = __shfl_xor(bs, m); const int oi = __shfl_xor(bi, m);
      if (os < bs || (os == bs && oi < bi)){ bs = os; bi = oi; }
    }
    const float thr = bs + MARGIN;
    for (int e = 0; e < 8; ++e){
      const float s = Ls[row][j*8+e];
      if (s <= thr){
        const int p = atomicAdd(&cnt[row], 1);
        if (p < CAP) cand[row][p] = Li[row][j*8+e];
      }
    }
    // if a stream's 4th-best is inside margin it may have dropped entries
    if (Ls[row][j*8+3] <= thr) ovf[row] = 1;
    if (Ls[row][j*8+7] <= thr) ovf[row] = 1;
  }
  __syncthreads();

  // ---- classify rows ----------------------------------------------------
  if (tid < 32){
    const int c = cnt[tid];
    if (ovf[tid] || c > CAP){
      cls[tid] = 2;
      bl[atomicAdd(&nbl, 1)] = tid;
      rl[atomicAdd(&nrl, 1)] = tid;
    } else if (c == 1){
      cls[tid] = 0; win[tid] = cand[tid][0];
    } else {
      cls[tid] = 1;
      rl[atomicAdd(&nrl, 1)] = tid;
      for (int q = 0; q < c; ++q){
        const int p = atomicAdd(&npairs, 1);
        pr[p] = tid; pc[p] = cand[tid][q];
      }
    }
  }
  __syncthreads();

  // ---- reconstruct exact np-fp32 residual for rows that need scoring ----
  const int NRL = nrl;
  for (int i = tid; i < NRL * DIM; i += 512){
    const int a = i >> 8, d = i & 255, row = rl[a];
    const size_t n = rowbase + row;
    float v = feat[n*DIM + d];
#pragma unroll
    for (int j2 = 0; j2 < LVL; ++j2){
      const int kj = idxw[(size_t)j2 * NROWS + n];
      v -= cb32[((size_t)j2 * KC + kj) * DIM + d];
    }
    Rres[row][d] = v;
  }
  __syncthreads();

  // ---- exact np-fp32 score per candidate pair ---------------------------
  const int NP = npairs;
  for (int p = tid; p < NP; p += 512){
    const int row = pr[p], ci = pc[p];
    float a = 0.f;
    for (int d = 0; d < DIM; ++d)
      a = fmaf(Rres[row][d], cb32[((size_t)LVL * KC + ci) * DIM + d], a);
    ps[p] = cnx_l[ci] - 2.0f * a;
  }
  __syncthreads();

  // ---- per-row selection (first-index tie-break) ------------------------
  if (tid < 32 && cls[tid] == 1){
    float bs = FLT_MAX; int bi = INT_MAX;
    for (int p = 0; p < NP; ++p) if (pr[p] == tid){
      const float sc = ps[p]; const int ci = pc[p];
      if (sc < bs || (sc == bs && ci < bi)){ bs = sc; bi = ci; }
    }
    win[tid] = bi;
  }
  // brute rows: wave 0, all 1024 centers with the exact fp32 chain
  if (wave == 0){
    for (int b = 0; b < nbl; ++b){
      const int row = bl[b];
      float bs = FLT_MAX; int bi = INT_MAX;
      for (int t = 0; t < 16; ++t){
        const int ci = t * 64 + lane;
        float a = 0.f;
        for (int d = 0; d < DIM; ++d)
          a = fmaf(Rres[row][d], cb32[((size_t)LVL * KC + ci) * DIM + d], a);
        const float sc = cnx_l[ci] - 2.0f * a;
        if (sc < bs || (sc == bs && ci < bi)){ bs = sc; bi = ci; }
      }
#pragma unroll
      for (int m = 1; m < 64; m <<= 1){
        const float ob = __shfl_xor(bs, m); const int oi = __shfl_xor(bi, m);
        if (ob < bs || (ob == bs && oi < bi)){ bs = ob; bi = oi; }
      }
      if (lane == 0) win[row] = bi;
    }
  }
  __syncthreads();

  // ---- update: elementwise fp32 chains in level order -------------------
  {
    const int row = tid >> 4, sub = tid & 15;
    const size_t n = rowbase + row;
    int hist[NLVL];
#pragma unroll
    for (int j2 = 0; j2 < LVL; ++j2) hist[j2] = idxw[(size_t)j2 * NROWS + n];
    hist[LVL] = win[row];
#pragma unroll
    for (int i = 0; i < 4; ++i){
      const int d = sub*4 + i*64;
      if (LVL < 3){
        float4 v = *reinterpret_cast<const float4*>(feat + n*DIM + d);
#pragma unroll
        for (int j2 = 0; j2 <= LVL; ++j2){
          const float4 q = *reinterpret_cast<const float4*>(
              cb32 + ((size_t)j2 * KC + hist[j2]) * DIM + d);
          v.x -= q.x; v.y -= q.y; v.z -= q.z; v.w -= q.w;
        }
        us4 u = { f2b(v.x), f2b(v.y), f2b(v.z), f2b(v.w) };
        *reinterpret_cast<us4*>(resb + n*DIM + d) = u;
      } else {
        float4 a = *reinterpret_cast<const float4*>(
            cb32 + ((size_t)0 * KC + hist[0]) * DIM + d);
#pragma unroll
        for (int j2 = 1; j2 < 4; ++j2){
          const float4 q = *reinterpret_cast<const float4*>(
              cb32 + ((size_t)j2 * KC + hist[j2]) * DIM + d);
          a.x += q.x; a.y += q.y; a.z += q.z; a.w += q.w;
        }
        *reinterpret_cast<float4*>(out + n*DIM + d) = a;
      }
    }
    if (sub == 0) idxw[(size_t)LVL * NROWS + n] = win[row];
  }
}

extern "C" void kernel_launch(void* const* d_in, const int* in_sizes, int n_in,
                              void* d_out, int out_size, void* d_ws, size_t ws_size,
                              hipStream_t stream){
  const float* feat = (const float*)d_in[0];
  const float* cb32 = (const float*)d_in[1];
  float* out = (float*)d_out;

  char* ws = (char*)d_ws;
  float* cnx = (float*)(ws);                                      // 4096*4 = 16384
  unsigned short* resb = (unsigned short*)(ws + 16384);           // N*D*2  = 67108864
  unsigned short* cbb  = (unsigned short*)(ws + 16384 + 67108864);// 2 MB
  int* idxw = (int*)(ws + 16384 + 67108864 + 2097152);            // 4*N*4  = 2 MB

  prep_cbb<<<1024, 256, 0, stream>>>(cb32, cbb);
  prep_cn<<<64, 64, 0, stream>>>(cb32, cnx);
  prep_res<<<32768, 256, 0, stream>>>(feat, resb);

  rvq_level<0><<<4096, 512, 0, stream>>>(feat, cb32, cbb + 0ul*KC*DIM, cnx + 0*KC, resb, idxw, out);
  rvq_level<1><<<4096, 512, 0, stream>>>(feat, cb32, cbb + 1ul*KC*DIM, cnx + 1*KC, resb, idxw, out);
  rvq_level<2><<<4096, 512, 0, stream>>>(feat, cb32, cbb + 2ul*KC*DIM, cnx + 2*KC, resb, idxw, out);
  rvq_level<3><<<4096, 512, 0, stream>>>(feat, cb32, cbb + 3ul*KC*DIM, cnx + 3*KC, resb, idxw, out);
}

// Round 5
// 1364.833 us; speedup vs baseline: 1.3783x; 1.3783x over previous
//
#include <hip/hip_runtime.h>
#include <hip/hip_bf16.h>
#include <hip/hip_fp16.h>
#include <float.h>
#include <limits.h>

#define NROWS 131072
#define DIM   256
#define NLVL  4
#define KC    1024
#define MARGIN 6.0f
#define CAP   16
#define REC   18        // record: row, cnt, cand[16]

typedef __attribute__((ext_vector_type(8))) short bf16x8;
typedef __attribute__((ext_vector_type(4))) float f32x4;
typedef __attribute__((ext_vector_type(4))) unsigned short us4;

__device__ __forceinline__ unsigned short f2b(float f){
  __hip_bfloat16 h = __float2bfloat16(f);
  return *reinterpret_cast<unsigned short*>(&h);
}

// square with a scheduling barrier so -ffp-contract can never fuse the
// multiply into a following add (numpy materializes cb*cb before summing)
__device__ __forceinline__ float sqb(float x){
  float s = x * x;
  asm volatile("" : "+v"(s));
  return s;
}

__device__ __forceinline__ float hmin2f(unsigned u){
  const float2 f = __half22float2(__builtin_bit_cast(__half2, u));
  return fminf(f.x, f.y);
}

// ---------------- prep kernels -----------------------------------------
__global__ void zero4(int* __restrict__ p){
  if (threadIdx.x < 4) p[threadIdx.x] = 0;
}

// bf16 copy of codebooks (phase-A input only)
__global__ void prep_cbb(const float* __restrict__ cb, unsigned short* __restrict__ cbb){
  const int wave = threadIdx.x >> 6, lane = threadIdx.x & 63;
  const int c = blockIdx.x * 4 + wave;                  // 0..4095
  const size_t off = (size_t)c * DIM + lane * 4;
  const float4 v = *reinterpret_cast<const float4*>(cb + off);
  us4 u = { f2b(v.x), f2b(v.y), f2b(v.z), f2b(v.w) };
  *reinterpret_cast<us4*>(cbb + off) = u;
}

// ||c||^2 replicating numpy fp32 pairwise_sum of materialized cb*cb (validated r4)
__global__ void prep_cn(const float* __restrict__ cb, float* __restrict__ cnx){
  const int c = blockIdx.x * 64 + threadIdx.x;          // 0..4095
  const float* p = cb + (size_t)c * DIM;
  float blk[2];
  for (int b = 0; b < 2; ++b){
    float r[8];
#pragma unroll
    for (int j = 0; j < 8; ++j) r[j] = sqb(p[b*128 + j]);
    for (int i = 8; i < 128; i += 8)
#pragma unroll
      for (int j = 0; j < 8; ++j) r[j] += sqb(p[b*128 + i + j]);
    blk[b] = ((r[0]+r[1]) + (r[2]+r[3])) + ((r[4]+r[5]) + (r[6]+r[7]));
  }
  cnx[c] = blk[0] + blk[1];
}

// ---------------- K1: MFMA scoring + candidate compaction --------------
// 64 rows/block, 8 waves; wave w scores centers [w*128,(w+1)*128).
// fp16 scores -> LDS [64][1032]; parallel min+margin scan; unique rows
// write idxw; ambiguous rows appended to global record list.
template<int LVL>
__global__ __launch_bounds__(512, 2)
void rvq_score(const float* __restrict__ feat,
               const unsigned short* __restrict__ resb,
               const unsigned short* __restrict__ cbb_l,
               const float* __restrict__ cnx_l,
               int* __restrict__ idxw,
               int* __restrict__ ambcnt,
               int* __restrict__ recs)
{
  __shared__ unsigned short s16[64*1032];
  __shared__ int rcnt[64];
  __shared__ int rcand[64][CAP];

  const int tid  = threadIdx.x;
  const int wave = tid >> 6, lane = tid & 63;
  const int r16  = lane & 15, quad = lane >> 4;
  const size_t rowbase = (size_t)blockIdx.x * 64;

  if (tid < 64) rcnt[tid] = 0;

  // ---- B fragments: 4 row-tiles (rows rt*16 + r16) --------------------
  bf16x8 Bf[4][8];
  if (LVL == 0){
#pragma unroll
    for (int rt = 0; rt < 4; ++rt)
#pragma unroll
      for (int kk = 0; kk < 8; ++kk){
        const float* p = feat + (rowbase + rt*16 + r16) * DIM + kk*32 + quad*8;
        const float4 f0 = *reinterpret_cast<const float4*>(p);
        const float4 f1 = *reinterpret_cast<const float4*>(p + 4);
        bf16x8 b;
        b[0]=(short)f2b(f0.x); b[1]=(short)f2b(f0.y); b[2]=(short)f2b(f0.z); b[3]=(short)f2b(f0.w);
        b[4]=(short)f2b(f1.x); b[5]=(short)f2b(f1.y); b[6]=(short)f2b(f1.z); b[7]=(short)f2b(f1.w);
        Bf[rt][kk] = b;
      }
  } else {
#pragma unroll
    for (int rt = 0; rt < 4; ++rt)
#pragma unroll
      for (int kk = 0; kk < 8; ++kk)
        Bf[rt][kk] = *reinterpret_cast<const bf16x8*>(
            resb + (rowbase + rt*16 + r16) * DIM + kk*32 + quad*8);
  }

  // ---- A double-buffered sweep over this wave's 128 centers -----------
  bf16x8 Af[2][8];
  float4 cn4[2];
  {
    const int c0 = wave * 128;
#pragma unroll
    for (int kk = 0; kk < 8; ++kk)
      Af[0][kk] = *reinterpret_cast<const bf16x8*>(
          cbb_l + (size_t)(c0 + r16) * DIM + kk*32 + quad*8);
    cn4[0] = *reinterpret_cast<const float4*>(cnx_l + c0 + quad*4);
  }

#pragma unroll
  for (int t = 0; t < 8; ++t){
    const int buf = t & 1;
    if (t < 7){
      const int c1 = wave * 128 + (t+1) * 16;
#pragma unroll
      for (int kk = 0; kk < 8; ++kk)
        Af[buf^1][kk] = *reinterpret_cast<const bf16x8*>(
            cbb_l + (size_t)(c1 + r16) * DIM + kk*32 + quad*8);
      cn4[buf^1] = *reinterpret_cast<const float4*>(cnx_l + c1 + quad*4);
    }
    f32x4 a0 = {0.f,0.f,0.f,0.f}, a1 = {0.f,0.f,0.f,0.f};
    f32x4 a2 = {0.f,0.f,0.f,0.f}, a3 = {0.f,0.f,0.f,0.f};
#pragma unroll
    for (int kk = 0; kk < 8; ++kk){
      a0 = __builtin_amdgcn_mfma_f32_16x16x32_bf16(Af[buf][kk], Bf[0][kk], a0, 0, 0, 0);
      a1 = __builtin_amdgcn_mfma_f32_16x16x32_bf16(Af[buf][kk], Bf[1][kk], a1, 0, 0, 0);
      a2 = __builtin_amdgcn_mfma_f32_16x16x32_bf16(Af[buf][kk], Bf[2][kk], a2, 0, 0, 0);
      a3 = __builtin_amdgcn_mfma_f32_16x16x32_bf16(Af[buf][kk], Bf[3][kk], a3, 0, 0, 0);
    }
    // D: col=lane&15 = residual row (within tile), row=quad*4+r = center
    const int c0 = wave * 128 + t * 16;
    const int col = c0 + quad * 4;
    const float4 cn = cn4[buf];
#pragma unroll
    for (int rt = 0; rt < 4; ++rt){
      const f32x4 a = (rt==0) ? a0 : (rt==1) ? a1 : (rt==2) ? a2 : a3;
      const float s0 = cn.x - 2.0f * a[0];
      const float s1 = cn.y - 2.0f * a[1];
      const float s2 = cn.z - 2.0f * a[2];
      const float s3 = cn.w - 2.0f * a[3];
      const unsigned w0 = __builtin_bit_cast(unsigned, __builtin_amdgcn_cvt_pkrtz(s0, s1));
      const unsigned w1 = __builtin_bit_cast(unsigned, __builtin_amdgcn_cvt_pkrtz(s2, s3));
      uint2 w = { w0, w1 };
      *reinterpret_cast<uint2*>(&s16[(size_t)(rt*16 + r16) * 1032 + col]) = w;
    }
  }
  __syncthreads();

  // ---- selection: 8 threads per row scan 1024 fp16 scores --------------
  const int srow = tid >> 3, sj = tid & 7;
  const unsigned short* rowp = s16 + (size_t)srow * 1032;
  float mn = FLT_MAX;
#pragma unroll
  for (int i = 0; i < 16; ++i){
    const int off = sj*128 + (((i + sj) & 15) << 3);
    const uint4 u = *reinterpret_cast<const uint4*>(rowp + off);
    mn = fminf(mn, fminf(fminf(hmin2f(u.x), hmin2f(u.y)),
                         fminf(hmin2f(u.z), hmin2f(u.w))));
  }
#pragma unroll
  for (int m = 1; m < 8; m <<= 1) mn = fminf(mn, __shfl_xor(mn, m));
  const float thrf = mn + MARGIN;

#pragma unroll
  for (int i = 0; i < 16; ++i){
    const int off = sj*128 + (((i + sj) & 15) << 3);
    const uint4 u = *reinterpret_cast<const uint4*>(rowp + off);
    const float cm = fminf(fminf(hmin2f(u.x), hmin2f(u.y)),
                           fminf(hmin2f(u.z), hmin2f(u.w)));
    if (cm <= thrf){
      const unsigned uu[4] = { u.x, u.y, u.z, u.w };
#pragma unroll
      for (int e = 0; e < 8; ++e){
        const unsigned short hv = (unsigned short)(uu[e >> 1] >> ((e & 1) * 16));
        const float f = __half2float(__builtin_bit_cast(__half, hv));
        if (f <= thrf){
          const int p = atomicAdd(&rcnt[srow], 1);
          if (p < CAP) rcand[srow][p] = off + e;
        }
      }
    }
  }
  __syncthreads();

  if (tid < 64){
    const int c = rcnt[tid];
    const int grow = (int)rowbase + tid;
    if (c == 1){
      idxw[LVL * NROWS + grow] = rcand[tid][0];
    } else {
      const int pos = atomicAdd(&ambcnt[LVL], 1);
      int* rp = recs + (size_t)pos * REC;
      rp[0] = grow; rp[1] = c;
      const int cc = c < CAP ? c : CAP;
      for (int q = 0; q < cc; ++q) rp[2+q] = rcand[tid][q];
    }
  }
}

// ---------------- K2: exact np-fp32 re-rank of compacted rows ----------
// 16 lanes per row, 16 groups per 256-thr block, grid-stride over records.
template<int LVL>
__global__ __launch_bounds__(256)
void rvq_rerank(const float* __restrict__ feat,
                const float* __restrict__ cb32,
                const float* __restrict__ cnx_l,
                int* __restrict__ idxw,
                const int* __restrict__ ambcnt,
                const int* __restrict__ recs)
{
  __shared__ float rres[16][260];
  const int tid = threadIdx.x;
  const int g = tid >> 4, q = tid & 15;
  const int cnt = ambcnt[LVL];
  const float* cbl = cb32 + (size_t)LVL * KC * DIM;

  for (int r = blockIdx.x * 16 + g; r < cnt; r += gridDim.x * 16){
    const int* rp = recs + (size_t)r * REC;
    const int grow = rp[0];
    const int c = rp[1];

    // exact fp32-chain residual (lane q owns d = q*16..q*16+15)
#pragma unroll
    for (int i4 = 0; i4 < 4; ++i4){
      const int d = q*16 + i4*4;
      float4 v = *reinterpret_cast<const float4*>(feat + (size_t)grow * DIM + d);
#pragma unroll
      for (int j2 = 0; j2 < LVL; ++j2){
        const int kj = idxw[(size_t)j2 * NROWS + grow];
        const float4 cv = *reinterpret_cast<const float4*>(
            cb32 + ((size_t)j2 * KC + kj) * DIM + d);
        v.x -= cv.x; v.y -= cv.y; v.z -= cv.z; v.w -= cv.w;
      }
      *reinterpret_cast<float4*>(&rres[g][d]) = v;
    }
    // wave-internal LDS write->read (compiler inserts lgkmcnt wait)

    float bs = FLT_MAX; int bi = INT_MAX;
    if (c <= CAP){
      if (q < c){
        const int ci = rp[2+q];
        float a = 0.f;
        for (int d4 = 0; d4 < 64; ++d4){
          const float4 cv = *reinterpret_cast<const float4*>(cbl + (size_t)ci * DIM + d4*4);
          const float4 rv = *reinterpret_cast<const float4*>(&rres[g][d4*4]);
          a = fmaf(rv.x, cv.x, a); a = fmaf(rv.y, cv.y, a);
          a = fmaf(rv.z, cv.z, a); a = fmaf(rv.w, cv.w, a);
        }
        bs = cnx_l[ci] - 2.0f * a; bi = ci;
      }
    } else {
      // overflow: brute-force all 1024 (lane q handles ci = q + 16*t, ascending)
      for (int t = 0; t < 64; ++t){
        const int ci = q + 16*t;
        float a = 0.f;
        for (int d4 = 0; d4 < 64; ++d4){
          const float4 cv = *reinterpret_cast<const float4*>(cbl + (size_t)ci * DIM + d4*4);
          const float4 rv = *reinterpret_cast<const float4*>(&rres[g][d4*4]);
          a = fmaf(rv.x, cv.x, a); a = fmaf(rv.y, cv.y, a);
          a = fmaf(rv.z, cv.z, a); a = fmaf(rv.w, cv.w, a);
        }
        const float sc = cnx_l[ci] - 2.0f * a;
        if (sc < bs){ bs = sc; bi = ci; }
      }
    }
#pragma unroll
    for (int m = 1; m < 16; m <<= 1){
      const float ob = __shfl_xor(bs, m); const int oi = __shfl_xor(bi, m);
      if (ob < bs || (ob == bs && oi < bi)){ bs = ob; bi = oi; }
    }
    if (q == 0) idxw[(size_t)LVL * NROWS + grow] = bi;
  }
}

// ---------------- K3: residual/output update (validated r4 semantics) --
template<int LVL>
__global__ __launch_bounds__(256)
void rvq_update(const float* __restrict__ feat,
                const float* __restrict__ cb32,
                const int* __restrict__ idxw,
                unsigned short* __restrict__ resb,
                float* __restrict__ out)
{
  const int tid = threadIdx.x;
  const int row = tid >> 4, sub = tid & 15;
  const size_t n = (size_t)blockIdx.x * 16 + row;
  int hist[NLVL];
#pragma unroll
  for (int j2 = 0; j2 <= LVL; ++j2) hist[j2] = idxw[(size_t)j2 * NROWS + n];
#pragma unroll
  for (int i = 0; i < 4; ++i){
    const int d = sub*4 + i*64;
    if (LVL < 3){
      float4 v = *reinterpret_cast<const float4*>(feat + n*DIM + d);
#pragma unroll
      for (int j2 = 0; j2 <= LVL; ++j2){
        const float4 qv = *reinterpret_cast<const float4*>(
            cb32 + ((size_t)j2 * KC + hist[j2]) * DIM + d);
        v.x -= qv.x; v.y -= qv.y; v.z -= qv.z; v.w -= qv.w;
      }
      us4 u = { f2b(v.x), f2b(v.y), f2b(v.z), f2b(v.w) };
      *reinterpret_cast<us4*>(resb + n*DIM + d) = u;
    } else {
      float4 a = *reinterpret_cast<const float4*>(
          cb32 + ((size_t)0 * KC + hist[0]) * DIM + d);
#pragma unroll
      for (int j2 = 1; j2 < 4; ++j2){
        const float4 qv = *reinterpret_cast<const float4*>(
            cb32 + ((size_t)j2 * KC + hist[j2]) * DIM + d);
        a.x += qv.x; a.y += qv.y; a.z += qv.z; a.w += qv.w;
      }
      *reinterpret_cast<float4*>(out + n*DIM + d) = a;
    }
  }
}

extern "C" void kernel_launch(void* const* d_in, const int* in_sizes, int n_in,
                              void* d_out, int out_size, void* d_ws, size_t ws_size,
                              hipStream_t stream){
  const float* feat = (const float*)d_in[0];
  const float* cb32 = (const float*)d_in[1];
  float* out = (float*)d_out;

  char* ws = (char*)d_ws;
  float* cnx  = (float*)(ws);                               // 16 KB
  int*   amb  = (int*)(ws + 16384);                         // 4 ints (pad to 16 KB)
  unsigned short* resb = (unsigned short*)(ws + 32768);     // 64 MB
  unsigned short* cbb  = (unsigned short*)(ws + 32768 + 67108864);       // 2 MB
  int*   idxw = (int*)(ws + 32768 + 67108864 + 2097152);                 // 2 MB
  int*   recs = (int*)(ws + 32768 + 67108864 + 2097152 + 2097152);       // 9 MB

  zero4<<<1, 64, 0, stream>>>(amb);
  prep_cbb<<<1024, 256, 0, stream>>>(cb32, cbb);
  prep_cn<<<64, 64, 0, stream>>>(cb32, cnx);

#define LVL_STEP(L) \
  rvq_score<L><<<2048, 512, 0, stream>>>(feat, resb, cbb + (size_t)L*KC*DIM, \
      cnx + L*KC, idxw, amb, recs); \
  rvq_rerank<L><<<512, 256, 0, stream>>>(feat, cb32, cnx + L*KC, idxw, amb, recs); \
  rvq_update<L><<<8192, 256, 0, stream>>>(feat, cb32, idxw, resb, out);

  LVL_STEP(0)
  LVL_STEP(1)
  LVL_STEP(2)
  LVL_STEP(3)
#undef LVL_STEP
}